// Round 7
// baseline (88.840 us; speedup 1.0000x reference)
//
#include <hip/hip_runtime.h>
#include <utility>

#define IMG_H 512
#define IMG_W 512

typedef _Float16 h2 __attribute__((ext_vector_type(2)));

__device__ __forceinline__ h2 h2min(h2 a, h2 b) { return __builtin_elementwise_min(a, b); }
__device__ __forceinline__ h2 h2max(h2 a, h2 b) { return __builtin_elementwise_max(a, b); }

// ---------------------------------------------------------------------------
// Compile-time linear program (round-3/4/5 validated machinery: Batcher
// sort/merge with symbolic +inf pads, backward pruning with min/max
// degradation, rank-selection identity for the final level).
// Round 6: 8-wide strip — two 4-wide groups sharing column sorts g0..g13
// and the 14-runs m(5,6), m(7,8) between their merge trees.
// Round 7: __launch_bounds__(256, 2) — the r6 profile showed VGPR_Count=76
// with ~100+ live h2 values (colv[98] + frames), i.e. forced scratch spills
// (VALUBusy collapsed 64%→30%). Cap at 2 waves/SIMD to give the allocator
// a ~256-VGPR budget and keep the whole program in registers.
// kinds: 0 ce(a,b)  1 mov v[a]=v[b]  2 load v[a]=cols[b]  3 store med[a]=v[b]
//        4 v[a]=min(v[a],v[b])       5 v[b]=max(v[a],v[b])
// ---------------------------------------------------------------------------
struct Op { int kind, a, b; };
constexpr int NSLOT = 352;
constexpr int MAXOPS = 4096;
struct Prog { Op ops[MAXOPS]; int n; bool ok; };

constexpr int pow2ceil(int x) { int p = 1; while (p < x) p += p; return p; }

struct Builder {
    Op ops[MAXOPS] = {};
    int n = 0;
    bool pad[NSLOT] = {};
    bool init[NSLOT] = {};
    bool ok = true;

    constexpr void emit(int k, int a, int b) {
        if (n < MAXOPS) ops[n++] = Op{k, a, b}; else ok = false;
    }
    constexpr void load(int s, int c) { emit(2, s, c); pad[s] = false; init[s] = true; }
    constexpr void mov(int d, int s) {
        if (!init[s]) ok = false;
        emit(1, d, s); pad[d] = pad[s]; init[d] = true;
    }
    constexpr void mkpad(int s) { pad[s] = true; init[s] = true; }
    constexpr void ce_(int a, int b) {
        if (!init[a] || !init[b]) { ok = false; return; }
        if (pad[a] && pad[b]) return;
        if (!pad[a] && pad[b]) return;                      // min stays low: no-op
        if (pad[a] && !pad[b]) {                            // value falls to a
            emit(1, a, b); pad[a] = false; pad[b] = true; return;
        }
        emit(0, a, b);
    }
    constexpr void maxin(int a, int b) {  // v[b] = max(v[a], v[b])
        if (!init[a] || !init[b] || pad[a] || pad[b]) ok = false;
        emit(5, a, b);
    }
    constexpr void minin(int a, int b) {  // v[a] = min(v[a], v[b])
        if (!init[a] || !init[b] || pad[a] || pad[b]) ok = false;
        emit(4, a, b);
    }
    constexpr void sort_run(int base, int len) {
        for (int p = 1; p < len; p += p)
            for (int k = p; k > 0; k /= 2)
                for (int j = k % p; j + k < len; j += k + k)
                    for (int i = 0; i < k; ++i)
                        if (i + j + k < len)
                            if ((i + j) / (p + p) == (i + j + k) / (p + p))
                                ce_(base + i + j, base + i + j + k);
    }
    constexpr void merge_stage(int base, int P) {
        int nn = 2 * P, p = P;
        for (int k = p; k > 0; k /= 2)
            for (int j = k % p; j + k < nn; j += k + k)
                for (int i = 0; i < k; ++i) {
                    int a = i + j, b = i + j + k;
                    if (b < nn && a / (p + p) == b / (p + p)) ce_(base + a, base + b);
                }
    }
    constexpr void load_col(int base, int c) {  // packed col c, sorted
        for (int r = 0; r < 7; ++r) load(base + r, c * 7 + r);
        sort_run(base, 7);
    }
    constexpr void place(int dst, int src, int len, int P) {
        for (int i = 0; i < len; ++i) mov(dst + i, src + i);
        for (int i = len; i < P; ++i) mkpad(dst + i);
    }
    // merge sorted runs (s1,l1),(s2,l2) into frame dst (2P slots); sources intact
    constexpr void merge_to(int dst, int s1, int l1, int s2, int l2) {
        int P = pow2ceil(l1 > l2 ? l1 : l2);
        place(dst, s1, l1, P);
        place(dst + P, s2, l2, P);
        merge_stage(dst, P);
    }
    // rank-24 of sorted-42 at A ∪ sorted-7 at B (min-of-max identity)
    constexpr void select_med49(int T, int A, int B, int o) {
        for (int t = 0; t < 7; ++t) {
            mov(T + t, A + 17 + t);
            maxin(B + 6 - t, T + t);
        }
        mov(T + 7, A + 24);
        minin(T, T + 1); minin(T + 2, T + 3);
        minin(T + 4, T + 5); minin(T + 6, T + 7);
        minin(T, T + 2); minin(T + 4, T + 6);
        minin(T, T + 4);
        if (!init[T] || pad[T]) ok = false;
        emit(3, o, T);
    }
};

constexpr Prog build() {
    Builder b{};
    // sorted columns g_c at 8c (c=0..13); merge frames:
    constexpr int M12 = 112, M34 = 128, M56 = 144, M78 = 160, M910 = 176, M1112 = 192;
    constexpr int C28A = 208, C28B = 240, C42 = 272, T0 = 336, T1 = 344;

    // ---- group A (outputs 0..3, cols g0..g9) ----
    for (int c = 1; c <= 8; ++c) b.load_col(8 * c, c);
    b.merge_to(M34, 8 * 3, 7, 8 * 4, 7);
    b.merge_to(M56, 8 * 5, 7, 8 * 6, 7);          // shared with group B
    b.merge_to(C28A, M34, 14, M56, 14);           // sorted(g3..g6)
    b.merge_to(M12, 8 * 1, 7, 8 * 2, 7);
    b.merge_to(M78, 8 * 7, 7, 8 * 8, 7);          // shared with group B

    b.merge_to(C42, C28A, 28, M12, 14);           // sorted42(g1..g6)
    b.load_col(8 * 0, 0);
    b.select_med49(T0, C42, 8 * 0, 0);            // out0: g0..g6
    b.select_med49(T1, C42, 8 * 7, 1);            // out1: g1..g7

    b.merge_to(C42, C28A, 28, M78, 14);           // sorted42(g3..g8)
    b.load_col(8 * 9, 9);
    b.select_med49(T0, C42, 8 * 2, 2);            // out2: g2..g8
    b.select_med49(T1, C42, 8 * 9, 3);            // out3: g3..g9

    // ---- group B (outputs 4..7, cols g4..g13) ----
    b.load_col(8 * 10, 10);
    b.merge_to(M910, 8 * 9, 7, 8 * 10, 7);
    b.merge_to(C28B, M78, 14, M910, 14);          // sorted(g7..g10)

    b.merge_to(C42, C28B, 28, M56, 14);           // sorted42(g5..g10)
    b.select_med49(T0, C42, 8 * 4, 4);            // out4: g4..g10
    b.load_col(8 * 11, 11);
    b.select_med49(T1, C42, 8 * 11, 5);           // out5: g5..g11

    b.load_col(8 * 12, 12);
    b.merge_to(M1112, 8 * 11, 7, 8 * 12, 7);
    b.merge_to(C42, C28B, 28, M1112, 14);         // sorted42(g7..g12)
    b.select_med49(T0, C42, 8 * 6, 6);            // out6: g6..g12
    b.load_col(8 * 13, 13);
    b.select_med49(T1, C42, 8 * 13, 7);           // out7: g7..g13

    // ---- backward prune + min/max degradation ----
    Prog p{};
    bool needed[NSLOT] = {};
    int kindr[MAXOPS] = {};
    bool keep[MAXOPS] = {};
    for (int t = b.n - 1; t >= 0; --t) {
        Op o = b.ops[t];
        if (o.kind == 3) { keep[t] = true; kindr[t] = 3; needed[o.b] = true; }
        else if (o.kind == 0) {
            bool na = needed[o.a], nb = needed[o.b];
            if (na && nb)      { keep[t] = true; kindr[t] = 0; }
            else if (na)       { keep[t] = true; kindr[t] = 4; needed[o.b] = true; }
            else if (nb)       { keep[t] = true; kindr[t] = 5; needed[o.a] = true; }
        } else if (o.kind == 1) {
            if (needed[o.a]) { keep[t] = true; kindr[t] = 1; needed[o.a] = false; needed[o.b] = true; }
        } else if (o.kind == 2) {
            if (needed[o.a]) { keep[t] = true; kindr[t] = 2; needed[o.a] = false; }
        } else if (o.kind == 4) {
            if (needed[o.a]) { keep[t] = true; kindr[t] = 4; needed[o.b] = true; }
        } else if (o.kind == 5) {
            if (needed[o.b]) { keep[t] = true; kindr[t] = 5; needed[o.a] = true; }
        }
    }
    p.n = 0;
    for (int t = 0; t < b.n; ++t)
        if (keep[t]) { p.ops[p.n] = b.ops[t]; p.ops[p.n].kind = kindr[t]; ++p.n; }
    p.ok = b.ok;
    return p;
}

constexpr Prog PROG = build();
static_assert(PROG.ok && PROG.n > 0 && PROG.n < MAXOPS, "program build failed");

template <int I>
__device__ __forceinline__ void step(h2* v, const h2* cols, h2* med) {
    constexpr Op o = PROG.ops[I];
    if constexpr (o.kind == 0) {
        h2 lo = h2min(v[o.a], v[o.b]);
        h2 hi = h2max(v[o.a], v[o.b]);
        v[o.a] = lo; v[o.b] = hi;
    } else if constexpr (o.kind == 1) v[o.a] = v[o.b];
    else if constexpr (o.kind == 2) v[o.a] = cols[o.b];
    else if constexpr (o.kind == 3) med[o.a] = v[o.b];
    else if constexpr (o.kind == 4) v[o.a] = h2min(v[o.a], v[o.b]);
    else v[o.b] = h2max(v[o.a], v[o.b]);
}

template <size_t... Is>
__device__ __forceinline__ void run_all(h2* v, const h2* cols, h2* med,
                                        std::index_sequence<Is...>) {
    (step<(int)Is>(v, cols, med), ...);
}

// Each thread: 8 (horizontal) x 2 (vertical, packed f16 halves) output pixels.
// launch_bounds min-waves/EU = 2: allow ~256 VGPR so colv[98]+frames stay in
// registers (r6 evidence: default heuristic allocated 76 VGPR and spilled).
__global__ __launch_bounds__(256, 2) void median7x7_kernel(
        const float* __restrict__ img, float* __restrict__ out) {
    const int bc = blockIdx.z;
    const int tx = threadIdx.x;                    // 0..63
    const int ty = threadIdx.y;                    // 0..3
    const int x0 = (blockIdx.x * 64 + tx) * 8;     // 0..504
    const int y  = (blockIdx.y * 4 + ty) * 2;      // 0..510

    const float* base = img + (size_t)bc * (IMG_H * IMG_W);
    const bool okl = (x0 >= 4);          // false only for tx == 0
    const bool okr = (x0 <= 496);        // false only for tx == 63
    const int xl = okl ? (x0 - 4) : 0;
    const int xr = okr ? (x0 + 8) : 504;

    // Packed columns: colv[c*7+d] = (img[y-3+d][gc], img[y-2+d][gc]),
    // gc = x0-3+c, c = 0..13.
    h2 colv[98];
    float prv[14];
#pragma unroll
    for (int r = 0; r < 8; ++r) {
        const int yy = y - 3 + r;
        float4 Q0, Q1, Q2, Q3;
        if ((unsigned)yy < IMG_H) {   // wave-uniform (blockDim.x == 64)
            const float* rp = base + (size_t)yy * IMG_W;
            Q0 = *(const float4*)(rp + xl);
            Q1 = *(const float4*)(rp + x0);
            Q2 = *(const float4*)(rp + x0 + 4);
            Q3 = *(const float4*)(rp + xr);
        } else {
            Q0 = make_float4(0.f, 0.f, 0.f, 0.f); Q1 = Q0; Q2 = Q0; Q3 = Q0;
        }
        float cur[14];
        cur[0] = okl ? Q0.y : 0.f; cur[1] = okl ? Q0.z : 0.f; cur[2] = okl ? Q0.w : 0.f;
        cur[3] = Q1.x; cur[4] = Q1.y; cur[5] = Q1.z; cur[6] = Q1.w;
        cur[7] = Q2.x; cur[8] = Q2.y; cur[9] = Q2.z; cur[10] = Q2.w;
        cur[11] = okr ? Q3.x : 0.f; cur[12] = okr ? Q3.y : 0.f; cur[13] = okr ? Q3.z : 0.f;
        if (r > 0) {
#pragma unroll
            for (int c = 0; c < 14; ++c)
                colv[c * 7 + (r - 1)] = (h2)__builtin_amdgcn_cvt_pkrtz(prv[c], cur[c]);
        }
#pragma unroll
        for (int c = 0; c < 14; ++c) prv[c] = cur[c];
    }

    h2 v[NSLOT];
    h2 med[8];
    run_all(v, colv, med, std::make_index_sequence<(size_t)PROG.n>{});

    float* op = out + (size_t)bc * (IMG_H * IMG_W) + (size_t)y * IMG_W + x0;
    *(float4*)op = make_float4((float)med[0].x, (float)med[1].x,
                               (float)med[2].x, (float)med[3].x);
    *(float4*)(op + 4) = make_float4((float)med[4].x, (float)med[5].x,
                                     (float)med[6].x, (float)med[7].x);
    *(float4*)(op + IMG_W) = make_float4((float)med[0].y, (float)med[1].y,
                                         (float)med[2].y, (float)med[3].y);
    *(float4*)(op + IMG_W + 4) = make_float4((float)med[4].y, (float)med[5].y,
                                             (float)med[6].y, (float)med[7].y);
}

extern "C" void kernel_launch(void* const* d_in, const int* in_sizes, int n_in,
                              void* d_out, int out_size, void* d_ws, size_t ws_size,
                              hipStream_t stream) {
    const float* img = (const float*)d_in[0];
    float* out = (float*)d_out;
    dim3 grid(1, 64, 24);
    dim3 block(64, 4, 1);
    hipLaunchKernelGGL(median7x7_kernel, grid, block, 0, stream, img, out);
}

// Round 8
// 88.674 us; speedup vs baseline: 1.0019x; 1.0019x over previous
//
#include <hip/hip_runtime.h>
#include <utility>

#define IMG_H 512
#define IMG_W 512

typedef _Float16 h2 __attribute__((ext_vector_type(2)));

__device__ __forceinline__ h2 h2min(h2 a, h2 b) { return __builtin_elementwise_min(a, b); }
__device__ __forceinline__ h2 h2max(h2 a, h2 b) { return __builtin_elementwise_max(a, b); }

// ---------------------------------------------------------------------------
// Compile-time linear program (r3..r6 validated machinery: Batcher sort/merge
// with symbolic +inf pads, backward pruning with min/max degradation,
// rank-selection identity at the final level; 8-wide strip with shared trees).
// Round 8: compile-time LINEAR-SCAN REGISTER ALLOCATION. r6 showed
// VGPR_Count=76 with ~100+ live h2 values and VALUBusy 30%; r7's
// launch_bounds(256,2) was bench-neutral => the h2 v[352] alloca is not
// being promoted (scratch round-trip per CE). Remap the sparse virtual slots
// onto a dense minimal physical set so the executor's array is small and
// provably SROA-able.
// kinds: 0 ce(a,b)  1 mov v[a]=v[b]  2 load v[a]=cols[b]  3 store med[a]=v[b]
//        4 v[a]=min(v[a],v[b])       5 v[b]=max(v[a],v[b])
// ---------------------------------------------------------------------------
struct Op { int kind, a, b; };
constexpr int NSLOT = 352;
constexpr int MAXOPS = 4096;
struct Prog { Op ops[MAXOPS]; int n; int nphys; bool ok; };

constexpr int pow2ceil(int x) { int p = 1; while (p < x) p += p; return p; }

struct Builder {
    Op ops[MAXOPS] = {};
    int n = 0;
    bool pad[NSLOT] = {};
    bool init[NSLOT] = {};
    bool ok = true;

    constexpr void emit(int k, int a, int b) {
        if (n < MAXOPS) ops[n++] = Op{k, a, b}; else ok = false;
    }
    constexpr void load(int s, int c) { emit(2, s, c); pad[s] = false; init[s] = true; }
    constexpr void mov(int d, int s) {
        if (!init[s] || d == s) ok = false;
        emit(1, d, s); pad[d] = pad[s]; init[d] = true;
    }
    constexpr void mkpad(int s) { pad[s] = true; init[s] = true; }
    constexpr void ce_(int a, int b) {
        if (!init[a] || !init[b]) { ok = false; return; }
        if (pad[a] && pad[b]) return;
        if (!pad[a] && pad[b]) return;                      // min stays low: no-op
        if (pad[a] && !pad[b]) {                            // value falls to a
            emit(1, a, b); pad[a] = false; pad[b] = true; return;
        }
        emit(0, a, b);
    }
    constexpr void maxin(int a, int b) {  // v[b] = max(v[a], v[b])
        if (!init[a] || !init[b] || pad[a] || pad[b]) ok = false;
        emit(5, a, b);
    }
    constexpr void minin(int a, int b) {  // v[a] = min(v[a], v[b])
        if (!init[a] || !init[b] || pad[a] || pad[b]) ok = false;
        emit(4, a, b);
    }
    constexpr void sort_run(int base, int len) {
        for (int p = 1; p < len; p += p)
            for (int k = p; k > 0; k /= 2)
                for (int j = k % p; j + k < len; j += k + k)
                    for (int i = 0; i < k; ++i)
                        if (i + j + k < len)
                            if ((i + j) / (p + p) == (i + j + k) / (p + p))
                                ce_(base + i + j, base + i + j + k);
    }
    constexpr void merge_stage(int base, int P) {
        int nn = 2 * P, p = P;
        for (int k = p; k > 0; k /= 2)
            for (int j = k % p; j + k < nn; j += k + k)
                for (int i = 0; i < k; ++i) {
                    int a = i + j, b = i + j + k;
                    if (b < nn && a / (p + p) == b / (p + p)) ce_(base + a, base + b);
                }
    }
    constexpr void load_col(int base, int c) {  // packed col c, sorted
        for (int r = 0; r < 7; ++r) load(base + r, c * 7 + r);
        sort_run(base, 7);
    }
    constexpr void place(int dst, int src, int len, int P) {
        for (int i = 0; i < len; ++i) mov(dst + i, src + i);
        for (int i = len; i < P; ++i) mkpad(dst + i);
    }
    constexpr void merge_to(int dst, int s1, int l1, int s2, int l2) {
        int P = pow2ceil(l1 > l2 ? l1 : l2);
        place(dst, s1, l1, P);
        place(dst + P, s2, l2, P);
        merge_stage(dst, P);
    }
    // rank-24 of sorted-42 at A ∪ sorted-7 at B (min-of-max identity)
    constexpr void select_med49(int T, int A, int B, int o) {
        for (int t = 0; t < 7; ++t) {
            mov(T + t, A + 17 + t);
            maxin(B + 6 - t, T + t);
        }
        mov(T + 7, A + 24);
        minin(T, T + 1); minin(T + 2, T + 3);
        minin(T + 4, T + 5); minin(T + 6, T + 7);
        minin(T, T + 2); minin(T + 4, T + 6);
        minin(T, T + 4);
        if (!init[T] || pad[T]) ok = false;
        emit(3, o, T);
    }
};

constexpr Prog build() {
    Builder b{};
    // sorted columns g_c at 8c (c=0..13); merge frames:
    constexpr int M12 = 112, M34 = 128, M56 = 144, M78 = 160, M910 = 176, M1112 = 192;
    constexpr int C28A = 208, C28B = 240, C42 = 272, T0 = 336, T1 = 344;

    // ---- group A (outputs 0..3, cols g0..g9) ----
    for (int c = 1; c <= 8; ++c) b.load_col(8 * c, c);
    b.merge_to(M34, 8 * 3, 7, 8 * 4, 7);
    b.merge_to(M56, 8 * 5, 7, 8 * 6, 7);          // shared with group B
    b.merge_to(C28A, M34, 14, M56, 14);           // sorted(g3..g6)
    b.merge_to(M12, 8 * 1, 7, 8 * 2, 7);
    b.merge_to(M78, 8 * 7, 7, 8 * 8, 7);          // shared with group B

    b.merge_to(C42, C28A, 28, M12, 14);           // sorted42(g1..g6)
    b.load_col(8 * 0, 0);
    b.select_med49(T0, C42, 8 * 0, 0);            // out0: g0..g6
    b.select_med49(T1, C42, 8 * 7, 1);            // out1: g1..g7

    b.merge_to(C42, C28A, 28, M78, 14);           // sorted42(g3..g8)
    b.load_col(8 * 9, 9);
    b.select_med49(T0, C42, 8 * 2, 2);            // out2: g2..g8
    b.select_med49(T1, C42, 8 * 9, 3);            // out3: g3..g9

    // ---- group B (outputs 4..7, cols g4..g13) ----
    b.load_col(8 * 10, 10);
    b.merge_to(M910, 8 * 9, 7, 8 * 10, 7);
    b.merge_to(C28B, M78, 14, M910, 14);          // sorted(g7..g10)

    b.merge_to(C42, C28B, 28, M56, 14);           // sorted42(g5..g10)
    b.select_med49(T0, C42, 8 * 4, 4);            // out4: g4..g10
    b.load_col(8 * 11, 11);
    b.select_med49(T1, C42, 8 * 11, 5);           // out5: g5..g11

    b.load_col(8 * 12, 12);
    b.merge_to(M1112, 8 * 11, 7, 8 * 12, 7);
    b.merge_to(C42, C28B, 28, M1112, 14);         // sorted42(g7..g12)
    b.select_med49(T0, C42, 8 * 6, 6);            // out6: g6..g12
    b.load_col(8 * 13, 13);
    b.select_med49(T1, C42, 8 * 13, 7);           // out7: g7..g13

    // ---- backward prune + min/max degradation ----
    Prog p{};
    bool needed[NSLOT] = {};
    int kindr[MAXOPS] = {};
    bool keep[MAXOPS] = {};
    for (int t = b.n - 1; t >= 0; --t) {
        Op o = b.ops[t];
        if (o.kind == 3) { keep[t] = true; kindr[t] = 3; needed[o.b] = true; }
        else if (o.kind == 0) {
            bool na = needed[o.a], nb = needed[o.b];
            if (na && nb)      { keep[t] = true; kindr[t] = 0; }
            else if (na)       { keep[t] = true; kindr[t] = 4; needed[o.b] = true; }
            else if (nb)       { keep[t] = true; kindr[t] = 5; needed[o.a] = true; }
        } else if (o.kind == 1) {
            if (needed[o.a]) { keep[t] = true; kindr[t] = 1; needed[o.a] = false; needed[o.b] = true; }
        } else if (o.kind == 2) {
            if (needed[o.a]) { keep[t] = true; kindr[t] = 2; needed[o.a] = false; }
        } else if (o.kind == 4) {
            if (needed[o.a]) { keep[t] = true; kindr[t] = 4; needed[o.b] = true; }
        } else if (o.kind == 5) {
            if (needed[o.b]) { keep[t] = true; kindr[t] = 5; needed[o.a] = true; }
        }
    }
    p.n = 0;
    for (int t = 0; t < b.n; ++t)
        if (keep[t]) { p.ops[p.n] = b.ops[t]; p.ops[p.n].kind = kindr[t]; ++p.n; }
    p.ok = b.ok;

    // ---- linear-scan register allocation: virtual -> dense physical ----
    // uses/defs: 0 ce: U{a,b} D{a,b} | 1 mov: U{b} D{a} | 2 load: D{a}
    //            3 store: U{b}       | 4 min: U{a,b} D{a} | 5 max: U{a,b} D{b}
    // Backward liveness -> last-use flags (post-op liveness).
    bool live[NSLOT] = {};
    bool lu_a[MAXOPS] = {};
    bool lu_b[MAXOPS] = {};
    for (int t = p.n - 1; t >= 0; --t) {
        Op o = p.ops[t];
        if (o.kind == 0 || o.kind == 4 || o.kind == 5) {
            lu_a[t] = !live[o.a]; lu_b[t] = !live[o.b];
        } else if (o.kind == 1 || o.kind == 3) {
            lu_b[t] = !live[o.b];
        }
        // kill defs
        if (o.kind == 0) { live[o.a] = false; live[o.b] = false; }
        else if (o.kind == 1 || o.kind == 2 || o.kind == 4) live[o.a] = false;
        else if (o.kind == 5) live[o.b] = false;
        // gen uses
        if (o.kind == 0 || o.kind == 4 || o.kind == 5) { live[o.a] = true; live[o.b] = true; }
        else if (o.kind == 1 || o.kind == 3) live[o.b] = true;
    }
    // In-place results must always be live afterwards (else prune failed).
    for (int t = 0; t < p.n; ++t) {
        Op o = p.ops[t];
        if (o.kind == 0 && (lu_a[t] || lu_b[t])) p.ok = false;
        if (o.kind == 4 && lu_a[t]) p.ok = false;
        if (o.kind == 5 && lu_b[t]) p.ok = false;
    }
    // Forward allocation with a LIFO free list.
    int phys[NSLOT] = {};
    bool bound[NSLOT] = {};
    int freelist[NSLOT] = {};
    int nfree = 0, nphys = 0;
    for (int t = 0; t < p.n; ++t) {
        Op o = p.ops[t];
        if (o.kind == 0) {                       // in-place both
            if (!bound[o.a] || !bound[o.b]) p.ok = false;
            p.ops[t].a = phys[o.a]; p.ops[t].b = phys[o.b];
        } else if (o.kind == 4) {                // a in-place, b pure source
            if (!bound[o.a] || !bound[o.b]) p.ok = false;
            p.ops[t].a = phys[o.a]; p.ops[t].b = phys[o.b];
            if (lu_b[t]) { freelist[nfree++] = phys[o.b]; bound[o.b] = false; }
        } else if (o.kind == 5) {                // b in-place, a pure source
            if (!bound[o.a] || !bound[o.b]) p.ok = false;
            p.ops[t].a = phys[o.a]; p.ops[t].b = phys[o.b];
            if (lu_a[t]) { freelist[nfree++] = phys[o.a]; bound[o.a] = false; }
        } else if (o.kind == 1) {                // mov a <- b
            if (!bound[o.b]) p.ok = false;
            int pb = phys[o.b];
            p.ops[t].b = pb;
            if (lu_b[t]) { freelist[nfree++] = pb; bound[o.b] = false; }
            if (bound[o.a]) { freelist[nfree++] = phys[o.a]; bound[o.a] = false; }
            int pa = (nfree > 0) ? freelist[--nfree] : nphys++;
            phys[o.a] = pa; bound[o.a] = true;
            p.ops[t].a = pa;
        } else if (o.kind == 2) {                // load a <- cols[b]
            if (bound[o.a]) { freelist[nfree++] = phys[o.a]; bound[o.a] = false; }
            int pa = (nfree > 0) ? freelist[--nfree] : nphys++;
            phys[o.a] = pa; bound[o.a] = true;
            p.ops[t].a = pa;                     // b stays a cols[] index
        } else {                                 // store med[a] <- v[b]
            if (!bound[o.b]) p.ok = false;
            p.ops[t].b = phys[o.b];
            if (lu_b[t]) { freelist[nfree++] = phys[o.b]; bound[o.b] = false; }
        }
        if (nphys > NSLOT || nfree > NSLOT) p.ok = false;
    }
    p.nphys = nphys;
    return p;
}

constexpr Prog PROG = build();
static_assert(PROG.ok && PROG.n > 0 && PROG.n < 2000, "program build failed");
static_assert(PROG.nphys > 0 && PROG.nphys <= 176, "regalloc blew up");
constexpr int NPHYS = PROG.nphys;

template <int I>
__device__ __forceinline__ void step(h2* v, const h2* cols, h2* med) {
    constexpr Op o = PROG.ops[I];
    if constexpr (o.kind == 0) {
        h2 lo = h2min(v[o.a], v[o.b]);
        h2 hi = h2max(v[o.a], v[o.b]);
        v[o.a] = lo; v[o.b] = hi;
    } else if constexpr (o.kind == 1) v[o.a] = v[o.b];
    else if constexpr (o.kind == 2) v[o.a] = cols[o.b];
    else if constexpr (o.kind == 3) med[o.a] = v[o.b];
    else if constexpr (o.kind == 4) v[o.a] = h2min(v[o.a], v[o.b]);
    else v[o.b] = h2max(v[o.a], v[o.b]);
}

template <size_t... Is>
__device__ __forceinline__ void run_all(h2* v, const h2* cols, h2* med,
                                        std::index_sequence<Is...>) {
    (step<(int)Is>(v, cols, med), ...);
}

// Each thread: 8 (horizontal) x 2 (vertical, packed f16 halves) output pixels.
__global__ __launch_bounds__(256, 2) void median7x7_kernel(
        const float* __restrict__ img, float* __restrict__ out) {
    const int bc = blockIdx.z;
    const int tx = threadIdx.x;                    // 0..63
    const int ty = threadIdx.y;                    // 0..3
    const int x0 = (blockIdx.x * 64 + tx) * 8;     // 0..504
    const int y  = (blockIdx.y * 4 + ty) * 2;      // 0..510

    const float* base = img + (size_t)bc * (IMG_H * IMG_W);
    const bool okl = (x0 >= 4);          // false only for tx == 0
    const bool okr = (x0 <= 496);        // false only for tx == 63
    const int xl = okl ? (x0 - 4) : 0;
    const int xr = okr ? (x0 + 8) : 504;

    // Packed columns: colv[c*7+d] = (img[y-3+d][gc], img[y-2+d][gc]),
    // gc = x0-3+c, c = 0..13.
    h2 colv[98];
    float prv[14];
#pragma unroll
    for (int r = 0; r < 8; ++r) {
        const int yy = y - 3 + r;
        float4 Q0, Q1, Q2, Q3;
        if ((unsigned)yy < IMG_H) {   // wave-uniform (blockDim.x == 64)
            const float* rp = base + (size_t)yy * IMG_W;
            Q0 = *(const float4*)(rp + xl);
            Q1 = *(const float4*)(rp + x0);
            Q2 = *(const float4*)(rp + x0 + 4);
            Q3 = *(const float4*)(rp + xr);
        } else {
            Q0 = make_float4(0.f, 0.f, 0.f, 0.f); Q1 = Q0; Q2 = Q0; Q3 = Q0;
        }
        float cur[14];
        cur[0] = okl ? Q0.y : 0.f; cur[1] = okl ? Q0.z : 0.f; cur[2] = okl ? Q0.w : 0.f;
        cur[3] = Q1.x; cur[4] = Q1.y; cur[5] = Q1.z; cur[6] = Q1.w;
        cur[7] = Q2.x; cur[8] = Q2.y; cur[9] = Q2.z; cur[10] = Q2.w;
        cur[11] = okr ? Q3.x : 0.f; cur[12] = okr ? Q3.y : 0.f; cur[13] = okr ? Q3.z : 0.f;
        if (r > 0) {
#pragma unroll
            for (int c = 0; c < 14; ++c)
                colv[c * 7 + (r - 1)] = (h2)__builtin_amdgcn_cvt_pkrtz(prv[c], cur[c]);
        }
#pragma unroll
        for (int c = 0; c < 14; ++c) prv[c] = cur[c];
    }

    h2 v[NPHYS];
    h2 med[8];
    run_all(v, colv, med, std::make_index_sequence<(size_t)PROG.n>{});

    float* op = out + (size_t)bc * (IMG_H * IMG_W) + (size_t)y * IMG_W + x0;
    *(float4*)op = make_float4((float)med[0].x, (float)med[1].x,
                               (float)med[2].x, (float)med[3].x);
    *(float4*)(op + 4) = make_float4((float)med[4].x, (float)med[5].x,
                                     (float)med[6].x, (float)med[7].x);
    *(float4*)(op + IMG_W) = make_float4((float)med[0].y, (float)med[1].y,
                                         (float)med[2].y, (float)med[3].y);
    *(float4*)(op + IMG_W + 4) = make_float4((float)med[4].y, (float)med[5].y,
                                             (float)med[6].y, (float)med[7].y);
}

extern "C" void kernel_launch(void* const* d_in, const int* in_sizes, int n_in,
                              void* d_out, int out_size, void* d_ws, size_t ws_size,
                              hipStream_t stream) {
    const float* img = (const float*)d_in[0];
    float* out = (float*)d_out;
    dim3 grid(1, 64, 24);
    dim3 block(64, 4, 1);
    hipLaunchKernelGGL(median7x7_kernel, grid, block, 0, stream, img, out);
}